// Round 1
// baseline (609.752 us; speedup 1.0000x reference)
//
#include <hip/hip_runtime.h>

#define DD 64

// ---------------- CSR build ----------------

__global__ __launch_bounds__(256) void transpose_w_kernel(
    const float* __restrict__ w_ih, const float* __restrict__ w_hh,
    float* __restrict__ wtih, float* __restrict__ wthh) {
  int idx = blockIdx.x * 256 + threadIdx.x;
  if (idx < 192 * 64) {
    // w[k][d] -> wt[d][k]
    wtih[(idx & 63) * 192 + (idx >> 6)] = w_ih[idx];
  } else if (idx < 2 * 192 * 64) {
    int i2 = idx - 192 * 64;
    wthh[(i2 & 63) * 192 + (i2 >> 6)] = w_hh[i2];
  }
}

__global__ __launch_bounds__(256) void count_kernel(
    const int* __restrict__ dst, unsigned* __restrict__ counts, int E) {
  int e = blockIdx.x * 256 + threadIdx.x;
  if (e < E) atomicAdd(&counts[dst[e]], 1u);
}

__global__ __launch_bounds__(1024) void scan_k1(
    const unsigned* __restrict__ counts, unsigned* __restrict__ offs,
    unsigned* __restrict__ bsums, int N) {
  __shared__ unsigned sm[1024];
  int tid = threadIdx.x;
  int i = blockIdx.x * 1024 + tid;
  unsigned v = (i < N) ? counts[i] : 0u;
  sm[tid] = v;
  __syncthreads();
  for (int ofs = 1; ofs < 1024; ofs <<= 1) {
    unsigned add = (tid >= ofs) ? sm[tid - ofs] : 0u;
    __syncthreads();
    sm[tid] += add;
    __syncthreads();
  }
  if (i < N) offs[i] = sm[tid] - v;  // exclusive within block
  if (tid == 0) bsums[blockIdx.x] = sm[1023];
}

__global__ __launch_bounds__(128) void scan_k2(
    unsigned* __restrict__ bsums, unsigned* __restrict__ offs, int M, int N) {
  __shared__ unsigned sm[128];
  int tid = threadIdx.x;
  unsigned v = (tid < M) ? bsums[tid] : 0u;
  sm[tid] = v;
  __syncthreads();
  for (int ofs = 1; ofs < 128; ofs <<= 1) {
    unsigned add = (tid >= ofs) ? sm[tid - ofs] : 0u;
    __syncthreads();
    sm[tid] += add;
    __syncthreads();
  }
  if (tid < M) bsums[tid] = sm[tid] - v;  // exclusive block offsets
  if (tid == 127) offs[N] = sm[127];      // grand total (padding is 0)
}

__global__ __launch_bounds__(256) void scan_k3(
    unsigned* __restrict__ offs, const unsigned* __restrict__ bsums,
    unsigned* __restrict__ cursor, int N) {
  int i = blockIdx.x * 256 + threadIdx.x;
  if (i < N) {
    unsigned o = offs[i] + bsums[i >> 10];
    offs[i] = o;
    cursor[i] = o;
  }
}

__global__ __launch_bounds__(256) void fill_kernel(
    const int* __restrict__ src, const int* __restrict__ dst,
    const int* __restrict__ rel, const float* __restrict__ norm,
    unsigned* __restrict__ cursor, unsigned* __restrict__ packed,
    float* __restrict__ norms, int E) {
  int e = blockIdx.x * 256 + threadIdx.x;
  if (e < E) {
    int d = dst[e];
    unsigned p = atomicAdd(&cursor[d], 1u);
    packed[p] = (unsigned)src[e] | ((unsigned)rel[e] << 20);
    norms[p] = norm[e];
  }
}

// ---------------- per-layer compute ----------------

// t[r][n][e] = sum_d x[n][d] * W[r][d][e]
__global__ __launch_bounds__(256) void transform_kernel(
    const float* __restrict__ x, const float* __restrict__ W,
    float* __restrict__ t, int N) {
  __shared__ float wl[3 * 64 * 64];
  for (int i = threadIdx.x; i < 3 * 64 * 64; i += 256) wl[i] = W[i];
  __syncthreads();
  int lane = threadIdx.x & 63;
  int n0 = __builtin_amdgcn_readfirstlane((blockIdx.x * 4 + (threadIdx.x >> 6)) * 4);
  if (n0 >= N) return;
  const float* xr = x + (size_t)n0 * DD;
  float acc[3][4] = {};
#pragma unroll 4
  for (int d = 0; d < 64; ++d) {
    float w0 = wl[d * 64 + lane];
    float w1 = wl[4096 + d * 64 + lane];
    float w2 = wl[8192 + d * 64 + lane];
#pragma unroll
    for (int j = 0; j < 4; ++j) {
      float xv = xr[j * 64 + d];  // wave-uniform -> s_load
      acc[0][j] = fmaf(xv, w0, acc[0][j]);
      acc[1][j] = fmaf(xv, w1, acc[1][j]);
      acc[2][j] = fmaf(xv, w2, acc[2][j]);
    }
  }
#pragma unroll
  for (int r = 0; r < 3; ++r)
#pragma unroll
    for (int j = 0; j < 4; ++j)
      t[((size_t)r * N + n0 + j) * DD + lane] = acc[r][j];
}

// swh[n][c] = sum_{edges e with dst==n} t[rel_e][src_e][c] * norm_e
__global__ __launch_bounds__(256) void gather_kernel(
    const float* __restrict__ t, const unsigned* __restrict__ offs,
    const unsigned* __restrict__ packed, const float* __restrict__ norms,
    float* __restrict__ swh, int N) {
  int lane = threadIdx.x & 63;
  int n = __builtin_amdgcn_readfirstlane(blockIdx.x * 4 + (threadIdx.x >> 6));
  if (n >= N) return;
  unsigned a = offs[n], b = offs[n + 1];
  float acc = 0.f;
  for (unsigned j = a; j < b; ++j) {
    unsigned p = packed[j];   // wave-uniform -> s_load
    float nv = norms[j];      // wave-uniform -> s_load
    int srcn = (int)(p & 0xFFFFFu);
    int r = (int)(p >> 20);
    acc = fmaf(t[((size_t)r * N + srcn) * DD + lane], nv, acc);
  }
  swh[(size_t)n * DD + lane] = acc;
}

// fused GRU cell: h' = (1-z)*n + z*h   (in-place on h buffer)
__global__ __launch_bounds__(256) void gru_kernel(
    const float* __restrict__ xin, const float* hin,
    const float* __restrict__ wtih_g, const float* __restrict__ wthh_g,
    const float* __restrict__ b_ih, const float* __restrict__ b_hh,
    float* hout, int N) {
  __shared__ float wl[64 * 192];  // wt_ih staged, 48KB
  for (int i = threadIdx.x; i < 64 * 192; i += 256) wl[i] = wtih_g[i];
  __syncthreads();
  int lane = threadIdx.x & 63;
  int n0 = __builtin_amdgcn_readfirstlane((blockIdx.x * 4 + (threadIdx.x >> 6)) * 4);
  if (n0 >= N) return;
  const float* xr = xin + (size_t)n0 * DD;
  const float* hr = hin + (size_t)n0 * DD;
  float ai[3][4] = {}, ah[3][4] = {};
#pragma unroll 4
  for (int d = 0; d < 64; ++d) {
    float wi0 = wl[d * 192 + lane];
    float wi1 = wl[d * 192 + 64 + lane];
    float wi2 = wl[d * 192 + 128 + lane];
    float wh0 = wthh_g[d * 192 + lane];
    float wh1 = wthh_g[d * 192 + 64 + lane];
    float wh2 = wthh_g[d * 192 + 128 + lane];
#pragma unroll
    for (int j = 0; j < 4; ++j) {
      float xv = xr[j * 64 + d];  // s_load
      float hv = hr[j * 64 + d];  // s_load
      ai[0][j] = fmaf(xv, wi0, ai[0][j]);
      ai[1][j] = fmaf(xv, wi1, ai[1][j]);
      ai[2][j] = fmaf(xv, wi2, ai[2][j]);
      ah[0][j] = fmaf(hv, wh0, ah[0][j]);
      ah[1][j] = fmaf(hv, wh1, ah[1][j]);
      ah[2][j] = fmaf(hv, wh2, ah[2][j]);
    }
  }
  float bi0 = b_ih[lane], bi1 = b_ih[64 + lane], bi2 = b_ih[128 + lane];
  float bh0 = b_hh[lane], bh1 = b_hh[64 + lane], bh2 = b_hh[128 + lane];
#pragma unroll
  for (int j = 0; j < 4; ++j) {
    float hprev = hr[(size_t)j * 64 + lane];
    float r = 1.f / (1.f + __expf(-(ai[0][j] + bi0 + ah[0][j] + bh0)));
    float z = 1.f / (1.f + __expf(-(ai[1][j] + bi1 + ah[1][j] + bh1)));
    float nn = tanhf(ai[2][j] + bi2 + r * (ah[2][j] + bh2));
    hout[((size_t)n0 + j) * DD + lane] = (1.f - z) * nn + z * hprev;
  }
}

// ---------------- batchnorm ----------------

__global__ __launch_bounds__(256) void bn_stats_kernel(
    const float* __restrict__ h, float* __restrict__ stats, int N) {
  int tid = threadIdx.x;
  int c = tid & 63;
  float s = 0.f, ss = 0.f;
  for (int n = blockIdx.x * 4 + (tid >> 6); n < N; n += gridDim.x * 4) {
    float v = h[(size_t)n * 64 + c];
    s += v;
    ss += v * v;
  }
  __shared__ float sm[2][256];
  sm[0][tid] = s;
  sm[1][tid] = ss;
  __syncthreads();
  if (tid < 64) {
    s = sm[0][tid] + sm[0][tid + 64] + sm[0][tid + 128] + sm[0][tid + 192];
    ss = sm[1][tid] + sm[1][tid + 64] + sm[1][tid + 128] + sm[1][tid + 192];
    atomicAdd(&stats[tid], s);
    atomicAdd(&stats[64 + tid], ss);
  }
}

__global__ __launch_bounds__(256) void bn_apply_kernel(
    float* out, const float* __restrict__ stats,
    const float* __restrict__ gamma, const float* __restrict__ beta,
    int N, int total) {
  int idx = blockIdx.x * 256 + threadIdx.x;
  if (idx >= total) return;
  int c = idx & 63;
  float invN = 1.f / (float)N;
  float mean = stats[c] * invN;
  float var = stats[64 + c] * invN - mean * mean;
  float sc = rsqrtf(var + 1e-5f) * gamma[c];
  float sh = beta[c] - mean * sc;
  out[idx] = out[idx] * sc + sh;
}

// ---------------- launch ----------------

extern "C" void kernel_launch(void* const* d_in, const int* in_sizes, int n_in,
                              void* d_out, int out_size, void* d_ws, size_t ws_size,
                              hipStream_t stream) {
  const float* h     = (const float*)d_in[0];
  const float* norm  = (const float*)d_in[1];
  const float* W     = (const float*)d_in[2];
  const float* w_ih  = (const float*)d_in[3];
  const float* w_hh  = (const float*)d_in[4];
  const float* b_ih  = (const float*)d_in[5];
  const float* b_hh  = (const float*)d_in[6];
  const float* gamma = (const float*)d_in[7];
  const float* beta  = (const float*)d_in[8];
  const int* src     = (const int*)d_in[9];
  const int* dst     = (const int*)d_in[10];
  const int* rel     = (const int*)d_in[11];
  float* out = (float*)d_out;

  const int N = in_sizes[0] / 64;
  const int E = in_sizes[1];

  char* w = (char*)d_ws;
  float* t = (float*)w;           w += (size_t)3 * N * 64 * 4;
  float* swh = (float*)w;         w += (size_t)N * 64 * 4;
  float* wtih = (float*)w;        w += 192 * 64 * 4;
  float* wthh = (float*)w;        w += 192 * 64 * 4;
  unsigned* offs = (unsigned*)w;  w += ((size_t)N + 4) * 4;
  unsigned* cursor = (unsigned*)w; w += (size_t)N * 4;
  unsigned* packed = (unsigned*)w; w += (size_t)E * 4;
  float* norms = (float*)w;       w += (size_t)E * 4;
  unsigned* bsums = (unsigned*)w; w += 128 * 4;
  float* stats = (float*)w;       w += 128 * 4;

  const int M = (N + 1023) / 1024;

  // init
  hipMemsetAsync(out, 0, (size_t)N * 64 * 4, stream);        // h0 = 0
  hipMemsetAsync(cursor, 0, (size_t)N * 4, stream);          // counts = 0
  hipMemsetAsync(stats, 0, 128 * 4, stream);

  transpose_w_kernel<<<96, 256, 0, stream>>>(w_ih, w_hh, wtih, wthh);

  // CSR over dst (graph is layer-invariant)
  count_kernel<<<(E + 255) / 256, 256, 0, stream>>>(dst, cursor, E);
  scan_k1<<<M, 1024, 0, stream>>>(cursor, offs, bsums, N);
  scan_k2<<<1, 128, 0, stream>>>(bsums, offs, M, N);
  scan_k3<<<(N + 255) / 256, 256, 0, stream>>>(offs, bsums, cursor, N);
  fill_kernel<<<(E + 255) / 256, 256, 0, stream>>>(src, dst, rel, norm, cursor,
                                                   packed, norms, E);

  for (int layer = 0; layer < 2; ++layer) {
    const float* xin = (layer == 0) ? h : out;
    transform_kernel<<<(N + 15) / 16, 256, 0, stream>>>(xin, W, t, N);
    gather_kernel<<<(N + 3) / 4, 256, 0, stream>>>(t, offs, packed, norms, swh, N);
    gru_kernel<<<(N + 15) / 16, 256, 0, stream>>>(swh, out, wtih, wthh, b_ih,
                                                  b_hh, out, N);
  }

  bn_stats_kernel<<<256, 256, 0, stream>>>(out, stats, N);
  int total = N * 64;
  bn_apply_kernel<<<(total + 255) / 256, 256, 0, stream>>>(out, stats, gamma,
                                                           beta, N, total);
}